// Round 2
// baseline (704.082 us; speedup 1.0000x reference)
//
#include <hip/hip_runtime.h>
#include <hip/hip_bf16.h>
#include <stdint.h>

// Problem constants
constexpr int kS = 2048;   // source length
constexpr int kN = 32;     // batch
constexpr int kH = 1024;   // hidden
constexpr int kE = 1024;   // mlp width
constexpr int kM = kS * kN;  // 65536 GEMM rows

// GEMM tiling
constexpr int BM = 128;
constexpr int BE = 128;
constexpr int BK = 64;
constexpr int KSTEPS = kH / BK;  // 16

typedef __bf16 bf16x8 __attribute__((ext_vector_type(8)));
typedef float f32x4 __attribute__((ext_vector_type(4)));

__device__ __forceinline__ float tanh_fast(float x) {
    // tanh(x) = 1 - 2/(e^{2x}+1); exp overflow/underflow saturates correctly.
    float e = __expf(2.0f * x);
    return 1.0f - 2.0f / (e + 1.0f);
}

__device__ __forceinline__ uint32_t f2bf_rne(float f) {
    uint32_t u = __builtin_bit_cast(uint32_t, f);
    u += 0x7FFFu + ((u >> 16) & 1u);
    return u >> 16;
}

__device__ __forceinline__ uint32_t pack2bf(float lo, float hi) {
    return f2bf_rne(lo) | (f2bf_rne(hi) << 16);
}

// ---------------- K1: h1c[n][e] = b1[e]+b2[e] + sum_h hidden_d[n][h]*W1[e][h]
__global__ __launch_bounds__(64) void k1_h1c(const float* __restrict__ hd,
                                             const float* __restrict__ W1,
                                             const float* __restrict__ b1,
                                             const float* __restrict__ b2,
                                             float* __restrict__ h1c) {
    int e = blockIdx.x;
    int lane = threadIdx.x;  // 0..63
    const float4* wrow = (const float4*)(W1 + (size_t)e * kH);
    float4 w[4];
#pragma unroll
    for (int q = 0; q < 4; ++q) w[q] = wrow[lane + q * 64];
    float bb = b1[e] + b2[e];
    for (int n = 0; n < kN; ++n) {
        const float4* hrow = (const float4*)(hd + (size_t)n * kH);
        float p = 0.f;
#pragma unroll
        for (int q = 0; q < 4; ++q) {
            float4 h4 = hrow[lane + q * 64];
            p += w[q].x * h4.x + w[q].y * h4.y + w[q].z * h4.z + w[q].w * h4.w;
        }
#pragma unroll
        for (int o = 32; o; o >>= 1) p += __shfl_xor(p, o);
        if (lane == 0) h1c[n * kE + e] = p + bb;
    }
}

// ---------------- K2: W2 fp32 -> bf16 (same [e][h] layout)
__global__ __launch_bounds__(256) void k2_cvt(const float* __restrict__ W2,
                                              unsigned short* __restrict__ W2b) {
    int i = blockIdx.x * 256 + threadIdx.x;  // float4 index, 262144 total
    float4 v = ((const float4*)W2)[i];
    uint2 o;
    o.x = pack2bf(v.x, v.y);
    o.y = pack2bf(v.z, v.w);
    ((uint2*)W2b)[i] = o;
}

// ---------------- K3: fused  a[r] += sum_e W3[e]*tanh(h1c[r&31][e] + out_e[r]@W2[e])
// 128x128 tile, BK=64, 4 waves (2x2), 16x16x32 bf16 MFMA, double-buffered LDS,
// XOR-swizzled LDS layout (byte ^= (row&7)<<4) -> conflict-free b128 reads.
__global__ __launch_bounds__(256, 2) void k3_gemm(const float* __restrict__ out_e,
                                                  const unsigned short* __restrict__ W2b,
                                                  const float* __restrict__ h1c,
                                                  const float* __restrict__ W3,
                                                  float* __restrict__ a_ws) {
    __shared__ __align__(16) unsigned short Abuf[2][BM * BK];
    __shared__ __align__(16) unsigned short Bbuf[2][BE * BK];

    const int tid = threadIdx.x;
    const int lane = tid & 63;
    const int w = tid >> 6;
    const int wr = w >> 1, wc = w & 1;
    const int l15 = lane & 15, lhi = lane >> 4;
    const int rowBase = (blockIdx.x >> 3) * BM;
    const int colBase = (blockIdx.x & 7) * BE;

    // accumulator init = h1c broadcast term (z = x@W2^T + h1c, applied pre-tanh)
    f32x4 acc[4][4];
#pragma unroll
    for (int m = 0; m < 4; ++m)
#pragma unroll
        for (int n = 0; n < 4; ++n)
#pragma unroll
            for (int j = 0; j < 4; ++j) {
                int rl = wr * 64 + m * 16 + lhi * 4 + j;
                int e = colBase + wc * 64 + n * 16 + l15;
                acc[m][n][j] = h1c[((rowBase + rl) & (kN - 1)) * kE + e];
            }

    auto stageA_load = [&](int ks, float4* regs) {
#pragma unroll
        for (int t = 0; t < 8; ++t) {
            int li = t * 256 + tid;
            int arow = li >> 4, akf = (li & 15) * 4;
            regs[t] = *(const float4*)(out_e + (size_t)(rowBase + arow) * kH + ks * BK + akf);
        }
    };
    auto stageB_load = [&](int ks, uint4* regs) {
#pragma unroll
        for (int t = 0; t < 4; ++t) {
            int li = t * 256 + tid;
            int brow = li >> 3, bk8 = (li & 7) * 8;
            regs[t] = *(const uint4*)(W2b + (size_t)(colBase + brow) * kH + ks * BK + bk8);
        }
    };
    auto stageA_write = [&](int buf, float4* regs) {
        char* base = (char*)Abuf[buf];
#pragma unroll
        for (int t = 0; t < 8; ++t) {
            int li = t * 256 + tid;
            int arow = li >> 4, akf = (li & 15) * 4;
            int off = arow * 128 + ((akf * 2) ^ ((arow & 7) << 4));
            uint2 val;
            val.x = pack2bf(regs[t].x, regs[t].y);
            val.y = pack2bf(regs[t].z, regs[t].w);
            *(uint2*)(base + off) = val;
        }
    };
    auto stageB_write = [&](int buf, uint4* regs) {
        char* base = (char*)Bbuf[buf];
#pragma unroll
        for (int t = 0; t < 4; ++t) {
            int li = t * 256 + tid;
            int brow = li >> 3, bk8 = (li & 7) * 8;
            int off = brow * 128 + ((bk8 * 2) ^ ((brow & 7) << 4));
            *(uint4*)(base + off) = regs[t];
        }
    };

    {
        float4 ar[8]; uint4 br[4];
        stageA_load(0, ar); stageB_load(0, br);
        stageA_write(0, ar); stageB_write(0, br);
    }
    __syncthreads();

    int cur = 0;
    for (int ks = 0; ks < KSTEPS; ++ks) {
        float4 ar[8]; uint4 br[4];
        if (ks + 1 < KSTEPS) { stageA_load(ks + 1, ar); stageB_load(ks + 1, br); }

        const char* Ab = (const char*)Abuf[cur];
        const char* Bb = (const char*)Bbuf[cur];
        bf16x8 af[2][4], bfr[2][4];
#pragma unroll
        for (int kk = 0; kk < 2; ++kk) {
            int kb = (kk * 32 + lhi * 8) * 2;  // byte offset of this lane's k chunk
#pragma unroll
            for (int m = 0; m < 4; ++m) {
                int row = wr * 64 + m * 16 + l15;
                uint4 v = *(const uint4*)(Ab + row * 128 + (kb ^ ((row & 7) << 4)));
                af[kk][m] = __builtin_bit_cast(bf16x8, v);
            }
#pragma unroll
            for (int n = 0; n < 4; ++n) {
                int row = wc * 64 + n * 16 + l15;
                uint4 v = *(const uint4*)(Bb + row * 128 + (kb ^ ((row & 7) << 4)));
                bfr[kk][n] = __builtin_bit_cast(bf16x8, v);
            }
        }
#pragma unroll
        for (int kk = 0; kk < 2; ++kk)
#pragma unroll
            for (int m = 0; m < 4; ++m)
#pragma unroll
                for (int n = 0; n < 4; ++n)
                    acc[m][n] = __builtin_amdgcn_mfma_f32_16x16x32_bf16(af[kk][m], bfr[kk][n],
                                                                        acc[m][n], 0, 0, 0);
        __syncthreads();
        if (ks + 1 < KSTEPS) {
            stageA_write(cur ^ 1, ar);
            stageB_write(cur ^ 1, br);
            __syncthreads();
            cur ^= 1;
        }
    }

    // epilogue: tanh + W3 dot + per-row reduce across the 16-lane col groups
    float w3v[4];
#pragma unroll
    for (int n = 0; n < 4; ++n) w3v[n] = W3[colBase + wc * 64 + n * 16 + l15];
    float rs[4][4];
#pragma unroll
    for (int m = 0; m < 4; ++m)
#pragma unroll
        for (int j = 0; j < 4; ++j) {
            float v = 0.f;
#pragma unroll
            for (int n = 0; n < 4; ++n) v += w3v[n] * tanh_fast(acc[m][n][j]);
#pragma unroll
            for (int o = 1; o < 16; o <<= 1) v += __shfl_xor(v, o);
            rs[m][j] = v;
        }
    if (l15 == 0) {
#pragma unroll
        for (int m = 0; m < 4; ++m)
#pragma unroll
            for (int j = 0; j < 4; ++j)
                atomicAdd(&a_ws[rowBase + wr * 64 + m * 16 + lhi * 4 + j], rs[m][j]);
    }
}

// ---------------- K4: alpha[s][n] = softmax over s of a[s][n]  (b3 invariant, dropped)
__global__ __launch_bounds__(256) void k4_softmax(const float* __restrict__ a_ws,
                                                  float* __restrict__ alpha) {
    int n = blockIdx.x;
    int tid = threadIdx.x;
    __shared__ float red[4];
    float v[8];
    float mx = -1e30f;
#pragma unroll
    for (int i = 0; i < 8; ++i) {
        v[i] = a_ws[(i * 256 + tid) * kN + n];
        mx = fmaxf(mx, v[i]);
    }
#pragma unroll
    for (int o = 32; o; o >>= 1) mx = fmaxf(mx, __shfl_xor(mx, o));
    if ((tid & 63) == 0) red[tid >> 6] = mx;
    __syncthreads();
    mx = fmaxf(fmaxf(red[0], red[1]), fmaxf(red[2], red[3]));
    float sum = 0.f;
#pragma unroll
    for (int i = 0; i < 8; ++i) { v[i] = __expf(v[i] - mx); sum += v[i]; }
#pragma unroll
    for (int o = 32; o; o >>= 1) sum += __shfl_xor(sum, o);
    __syncthreads();
    if ((tid & 63) == 0) red[tid >> 6] = sum;
    __syncthreads();
    sum = red[0] + red[1] + red[2] + red[3];
    float inv = 1.0f / sum;
#pragma unroll
    for (int i = 0; i < 8; ++i) alpha[(i * 256 + tid) * kN + n] = v[i] * inv;
}

// ---------------- K5: partial c over s-chunks of 128
__global__ __launch_bounds__(256) void k5_part(const float* __restrict__ out_e,
                                               const float* __restrict__ alpha,
                                               float* __restrict__ c_part) {
    int n = blockIdx.x & 31;
    int sc = blockIdx.x >> 5;
    int tid = threadIdx.x;
    float4 acc = make_float4(0.f, 0.f, 0.f, 0.f);
    for (int s = sc * 128; s < sc * 128 + 128; ++s) {
        float al = alpha[s * kN + n];
        float4 x = *(const float4*)(out_e + ((size_t)s * kN + n) * kH + tid * 4);
        acc.x += al * x.x; acc.y += al * x.y; acc.z += al * x.z; acc.w += al * x.w;
    }
    *(float4*)(c_part + ((size_t)sc * kN + n) * kH + tid * 4) = acc;
}

// ---------------- K6: reduce partials -> c[n][h]
__global__ __launch_bounds__(256) void k6_reduce(const float* __restrict__ c_part,
                                                 float* __restrict__ c) {
    int idx = blockIdx.x * 256 + threadIdx.x;  // float4 index over 8192
    float4 acc = make_float4(0.f, 0.f, 0.f, 0.f);
#pragma unroll
    for (int scn = 0; scn < 16; ++scn) {
        float4 x = ((const float4*)c_part)[scn * 8192 + idx];
        acc.x += x.x; acc.y += x.y; acc.z += x.z; acc.w += x.w;
    }
    ((float4*)c)[idx] = acc;
}

extern "C" void kernel_launch(void* const* d_in, const int* in_sizes, int n_in,
                              void* d_out, int out_size, void* d_ws, size_t ws_size,
                              hipStream_t stream) {
    const float* out_e = (const float*)d_in[0];
    const float* hidden_d = (const float*)d_in[1];
    const float* W1 = (const float*)d_in[2];
    const float* b1 = (const float*)d_in[3];
    const float* W2 = (const float*)d_in[4];
    const float* b2 = (const float*)d_in[5];
    const float* W3 = (const float*)d_in[6];
    // b3 (d_in[7]) is softmax-invariant -> unused.

    float* out = (float*)d_out;
    float* c_out = out;                 // (1,N,H) = 32768 floats
    float* alpha_out = out + kN * kH;   // (S,N,1) = 65536 floats

    char* ws = (char*)d_ws;
    unsigned short* W2b = (unsigned short*)ws;                       // 2 MB
    float* h1c = (float*)(ws + (2u << 20));                          // 128 KB
    float* a_ws = (float*)(ws + (2u << 20) + (128u << 10));          // 256 KB
    float* c_part = (float*)(ws + (2u << 20) + (384u << 10));        // 2 MB
    // total ws use ~4.5 MB

    k1_h1c<<<kE, 64, 0, stream>>>(hidden_d, W1, b1, b2, h1c);
    k2_cvt<<<(kE * kH / 4) / 256, 256, 0, stream>>>(W2, W2b);
    (void)hipMemsetAsync(a_ws, 0, kM * sizeof(float), stream);
    k3_gemm<<<(kM / BM) * (kE / BE), 256, 0, stream>>>(out_e, W2b, h1c, W3, a_ws);
    k4_softmax<<<kN, 256, 0, stream>>>(a_ws, alpha_out);
    k5_part<<<16 * kN, 256, 0, stream>>>(out_e, alpha_out, c_part);
    k6_reduce<<<32, 256, 0, stream>>>(c_part, c_out);
}

// Round 4
// 683.341 us; speedup vs baseline: 1.0304x; 1.0304x over previous
//
#include <hip/hip_runtime.h>
#include <hip/hip_bf16.h>
#include <stdint.h>

// Problem constants
constexpr int kS = 2048;   // source length
constexpr int kN = 32;     // batch
constexpr int kH = 1024;   // hidden
constexpr int kE = 1024;   // mlp width
constexpr int kM = kS * kN;  // 65536 GEMM rows

// GEMM tiling
constexpr int BM = 128;
constexpr int BE = 128;
constexpr int BK = 64;
constexpr int KSTEPS = kH / BK;  // 16

typedef __bf16 bf16x8 __attribute__((ext_vector_type(8)));
typedef float f32x4 __attribute__((ext_vector_type(4)));

__device__ __forceinline__ float tanh_fast(float x) {
    float e = __expf(2.0f * x);
    return 1.0f - 2.0f / (e + 1.0f);
}

__device__ __forceinline__ uint32_t f2bf_rne(float f) {
    uint32_t u = __builtin_bit_cast(uint32_t, f);
    u += 0x7FFFu + ((u >> 16) & 1u);
    return u >> 16;
}

__device__ __forceinline__ uint32_t pack2bf(float lo, float hi) {
    return f2bf_rne(lo) | (f2bf_rne(hi) << 16);
}

// async global->LDS, 16B per lane, wave-uniform LDS base (HW adds lane*16)
__device__ __forceinline__ void gl_lds16(const void* g, void* l) {
    __builtin_amdgcn_global_load_lds(
        (const __attribute__((address_space(1))) uint32_t*)g,
        (__attribute__((address_space(3))) uint32_t*)l, 16, 0, 0);
}

// ---------------- K0: out_e fp32 -> bf16 copy (A operand for the GEMM)
__global__ __launch_bounds__(256) void k0_cvtA(const float* __restrict__ in,
                                               unsigned short* __restrict__ out) {
    size_t i = (size_t)blockIdx.x * 256 + threadIdx.x;  // float4 index
    float4 v = ((const float4*)in)[i];
    uint2 o;
    o.x = pack2bf(v.x, v.y);
    o.y = pack2bf(v.z, v.w);
    ((uint2*)out)[i] = o;
}

// ---------------- K1: h1c[n][e] = b1[e]+b2[e] + sum_h hidden_d[n][h]*W1[e][h]
__global__ __launch_bounds__(64) void k1_h1c(const float* __restrict__ hd,
                                             const float* __restrict__ W1,
                                             const float* __restrict__ b1,
                                             const float* __restrict__ b2,
                                             float* __restrict__ h1c) {
    int e = blockIdx.x;
    int lane = threadIdx.x;
    const float4* wrow = (const float4*)(W1 + (size_t)e * kH);
    float4 w[4];
#pragma unroll
    for (int q = 0; q < 4; ++q) w[q] = wrow[lane + q * 64];
    float bb = b1[e] + b2[e];
    for (int n = 0; n < kN; ++n) {
        const float4* hrow = (const float4*)(hd + (size_t)n * kH);
        float p = 0.f;
#pragma unroll
        for (int q = 0; q < 4; ++q) {
            float4 h4 = hrow[lane + q * 64];
            p += w[q].x * h4.x + w[q].y * h4.y + w[q].z * h4.z + w[q].w * h4.w;
        }
#pragma unroll
        for (int o = 32; o; o >>= 1) p += __shfl_xor(p, o);
        if (lane == 0) h1c[n * kE + e] = p + bb;
    }
}

// ---------------- K2: W2 fp32 -> bf16 (same [e][h] layout)
__global__ __launch_bounds__(256) void k2_cvt(const float* __restrict__ W2,
                                              unsigned short* __restrict__ W2b) {
    int i = blockIdx.x * 256 + threadIdx.x;
    float4 v = ((const float4*)W2)[i];
    uint2 o;
    o.x = pack2bf(v.x, v.y);
    o.y = pack2bf(v.z, v.w);
    ((uint2*)W2b)[i] = o;
}

// ---------------- K3: fused  a[r] = sum_e W3[e]*tanh(h1c[r&31][e] + out_e[r]@W2[e])
// 128x128 tile, BK=64, 4 waves (2x2), 16x16x32 bf16 MFMA, double-buffered LDS.
// DIRECT=true: A pre-converted bf16, both operands staged with global_load_lds;
// XOR swizzle realized by pre-swizzling the per-lane GLOBAL source chunk
// (rule #21: linear DMA dest + inverse-swizzled source + swizzled ds_read).
template <bool DIRECT>
__global__ __launch_bounds__(256, 2) void k3_gemm(const float* __restrict__ out_e,
                                                  const unsigned short* __restrict__ Abf,
                                                  const unsigned short* __restrict__ W2b,
                                                  const float* __restrict__ h1c,
                                                  const float* __restrict__ W3,
                                                  float* __restrict__ a_ws) {
    __shared__ __align__(16) unsigned short Abuf[2][BM * BK];
    __shared__ __align__(16) unsigned short Bbuf[2][BE * BK];

    const int tid = threadIdx.x;
    const int lane = tid & 63;
    const int w = tid >> 6;
    const int wr = w >> 1, wc = w & 1;
    const int l15 = lane & 15, lhi = lane >> 4;
    const int rowBase = (blockIdx.x >> 3) * BM;
    const int colBase = (blockIdx.x & 7) * BE;

    // accumulator init = h1c broadcast term (z = x@W2^T + h1c, applied pre-tanh)
    f32x4 acc[4][4];
#pragma unroll
    for (int m = 0; m < 4; ++m)
#pragma unroll
        for (int n = 0; n < 4; ++n)
#pragma unroll
            for (int j = 0; j < 4; ++j) {
                int rl = wr * 64 + m * 16 + lhi * 4 + j;
                int e = colBase + wc * 64 + n * 16 + l15;
                acc[m][n][j] = h1c[((rowBase + rl) & (kN - 1)) * kE + e];
            }

    // ---- DIRECT staging: 16 KB tile = 4 issues/wave; source chunk pre-swizzled.
    // LDS linear offset L = w*4096 + i*1024 + lane*16 -> row = L>>7, chunk c=(L>>4)&7.
    // Want LDS chunk c of row r to hold source chunk c^(r&7); r&7 == lane>>3.
    const int r8 = lane >> 3;
    const int schunk = (lane & 7) ^ r8;  // source 16B-chunk index
    auto stage_dma = [&](const unsigned short* src, int gRowBase, int ks, int buf,
                         unsigned short(*ldsArr)[BM * BK]) {
#pragma unroll
        for (int i = 0; i < 4; ++i) {
            int row = w * 32 + i * 8 + r8;
            const void* g = src + (size_t)(gRowBase + row) * kH + ks * BK + schunk * 8;
            void* l = (char*)ldsArr[buf] + w * 4096 + i * 1024;
            gl_lds16(g, l);
        }
    };

    // ---- fallback reg staging (fp32 A path)
    auto stageA_load = [&](int ks, float4* regs) {
#pragma unroll
        for (int t = 0; t < 8; ++t) {
            int li = t * 256 + tid;
            int arow = li >> 4, akf = (li & 15) * 4;
            regs[t] = *(const float4*)(out_e + (size_t)(rowBase + arow) * kH + ks * BK + akf);
        }
    };
    auto stageB_load = [&](int ks, uint4* regs) {
#pragma unroll
        for (int t = 0; t < 4; ++t) {
            int li = t * 256 + tid;
            int brow = li >> 3, bk8 = (li & 7) * 8;
            regs[t] = *(const uint4*)(W2b + (size_t)(colBase + brow) * kH + ks * BK + bk8);
        }
    };
    auto stageA_write = [&](int buf, float4* regs) {
        char* base = (char*)Abuf[buf];
#pragma unroll
        for (int t = 0; t < 8; ++t) {
            int li = t * 256 + tid;
            int arow = li >> 4, akf = (li & 15) * 4;
            int off = arow * 128 + ((akf * 2) ^ ((arow & 7) << 4));
            uint2 val;
            val.x = pack2bf(regs[t].x, regs[t].y);
            val.y = pack2bf(regs[t].z, regs[t].w);
            *(uint2*)(base + off) = val;
        }
    };
    auto stageB_write = [&](int buf, uint4* regs) {
        char* base = (char*)Bbuf[buf];
#pragma unroll
        for (int t = 0; t < 4; ++t) {
            int li = t * 256 + tid;
            int brow = li >> 3, bk8 = (li & 7) * 8;
            int off = brow * 128 + ((bk8 * 2) ^ ((brow & 7) << 4));
            *(uint4*)(base + off) = regs[t];
        }
    };

    auto compute = [&](int cur) {
        const char* Ab = (const char*)Abuf[cur];
        const char* Bb = (const char*)Bbuf[cur];
        bf16x8 af[2][4], bfr[2][4];
#pragma unroll
        for (int kk = 0; kk < 2; ++kk) {
            int kb = (kk * 32 + lhi * 8) * 2;
#pragma unroll
            for (int m = 0; m < 4; ++m) {
                int row = wr * 64 + m * 16 + l15;
                uint4 v = *(const uint4*)(Ab + row * 128 + (kb ^ ((row & 7) << 4)));
                af[kk][m] = __builtin_bit_cast(bf16x8, v);
            }
#pragma unroll
            for (int n = 0; n < 4; ++n) {
                int row = wc * 64 + n * 16 + l15;
                uint4 v = *(const uint4*)(Bb + row * 128 + (kb ^ ((row & 7) << 4)));
                bfr[kk][n] = __builtin_bit_cast(bf16x8, v);
            }
        }
#pragma unroll
        for (int kk = 0; kk < 2; ++kk)
#pragma unroll
            for (int m = 0; m < 4; ++m)
#pragma unroll
                for (int n = 0; n < 4; ++n)
                    acc[m][n] = __builtin_amdgcn_mfma_f32_16x16x32_bf16(af[kk][m], bfr[kk][n],
                                                                        acc[m][n], 0, 0, 0);
    };

    if (DIRECT) {
        stage_dma(Abf, rowBase, 0, 0, Abuf);
        stage_dma(W2b, colBase, 0, 0, Bbuf);
        __syncthreads();  // drains vmcnt(0) -> buf0 ready
        int cur = 0;
#pragma unroll 4
        for (int ks = 0; ks < KSTEPS; ++ks) {
            if (ks + 1 < KSTEPS) {
                stage_dma(Abf, rowBase, ks + 1, cur ^ 1, Abuf);
                stage_dma(W2b, colBase, ks + 1, cur ^ 1, Bbuf);
            }
            compute(cur);
            __syncthreads();  // drains vmcnt -> buf^1 ready; protects buf reuse
            cur ^= 1;
        }
    } else {
        {
            float4 ar[8]; uint4 br[4];
            stageA_load(0, ar); stageB_load(0, br);
            stageA_write(0, ar); stageB_write(0, br);
        }
        __syncthreads();
        int cur = 0;
        for (int ks = 0; ks < KSTEPS; ++ks) {
            float4 ar[8]; uint4 br[4];
            if (ks + 1 < KSTEPS) { stageA_load(ks + 1, ar); stageB_load(ks + 1, br); }
            compute(cur);
            __syncthreads();
            if (ks + 1 < KSTEPS) {
                stageA_write(cur ^ 1, ar);
                stageB_write(cur ^ 1, br);
                __syncthreads();
                cur ^= 1;
            }
        }
    }

    // epilogue: tanh + W3 dot + per-row reduce across the 16-lane col groups
    float w3v[4];
#pragma unroll
    for (int n = 0; n < 4; ++n) w3v[n] = W3[colBase + wc * 64 + n * 16 + l15];
    float rs[4][4];
#pragma unroll
    for (int m = 0; m < 4; ++m)
#pragma unroll
        for (int j = 0; j < 4; ++j) {
            float v = 0.f;
#pragma unroll
            for (int n = 0; n < 4; ++n) v += w3v[n] * tanh_fast(acc[m][n][j]);
#pragma unroll
            for (int o = 1; o < 16; o <<= 1) v += __shfl_xor(v, o);
            rs[m][j] = v;
        }
    if (l15 == 0) {
#pragma unroll
        for (int m = 0; m < 4; ++m)
#pragma unroll
            for (int j = 0; j < 4; ++j)
                atomicAdd(&a_ws[rowBase + wr * 64 + m * 16 + lhi * 4 + j], rs[m][j]);
    }
}

// ---------------- K4: alpha[s][n] = softmax over s of a[s][n]
__global__ __launch_bounds__(256) void k4_softmax(const float* __restrict__ a_ws,
                                                  float* __restrict__ alpha) {
    int n = blockIdx.x;
    int tid = threadIdx.x;
    __shared__ float red[4];
    float v[8];
    float mx = -1e30f;
#pragma unroll
    for (int i = 0; i < 8; ++i) {
        v[i] = a_ws[(i * 256 + tid) * kN + n];
        mx = fmaxf(mx, v[i]);
    }
#pragma unroll
    for (int o = 32; o; o >>= 1) mx = fmaxf(mx, __shfl_xor(mx, o));
    if ((tid & 63) == 0) red[tid >> 6] = mx;
    __syncthreads();
    mx = fmaxf(fmaxf(red[0], red[1]), fmaxf(red[2], red[3]));
    float sum = 0.f;
#pragma unroll
    for (int i = 0; i < 8; ++i) { v[i] = __expf(v[i] - mx); sum += v[i]; }
#pragma unroll
    for (int o = 32; o; o >>= 1) sum += __shfl_xor(sum, o);
    __syncthreads();
    if ((tid & 63) == 0) red[tid >> 6] = sum;
    __syncthreads();
    sum = red[0] + red[1] + red[2] + red[3];
    float inv = 1.0f / sum;
#pragma unroll
    for (int i = 0; i < 8; ++i) alpha[(i * 256 + tid) * kN + n] = v[i] * inv;
}

// ---------------- K5: partial c over s-chunks of 128
__global__ __launch_bounds__(256) void k5_part(const float* __restrict__ out_e,
                                               const float* __restrict__ alpha,
                                               float* __restrict__ c_part) {
    int n = blockIdx.x & 31;
    int sc = blockIdx.x >> 5;
    int tid = threadIdx.x;
    float4 acc = make_float4(0.f, 0.f, 0.f, 0.f);
    for (int s = sc * 128; s < sc * 128 + 128; ++s) {
        float al = alpha[s * kN + n];
        float4 x = *(const float4*)(out_e + ((size_t)s * kN + n) * kH + tid * 4);
        acc.x += al * x.x; acc.y += al * x.y; acc.z += al * x.z; acc.w += al * x.w;
    }
    *(float4*)(c_part + ((size_t)sc * kN + n) * kH + tid * 4) = acc;
}

// ---------------- K6: reduce partials -> c[n][h]
__global__ __launch_bounds__(256) void k6_reduce(const float* __restrict__ c_part,
                                                 float* __restrict__ c) {
    int idx = blockIdx.x * 256 + threadIdx.x;
    float4 acc = make_float4(0.f, 0.f, 0.f, 0.f);
#pragma unroll
    for (int scn = 0; scn < 16; ++scn) {
        float4 x = ((const float4*)c_part)[scn * 8192 + idx];
        acc.x += x.x; acc.y += x.y; acc.z += x.z; acc.w += x.w;
    }
    ((float4*)c)[idx] = acc;
}

extern "C" void kernel_launch(void* const* d_in, const int* in_sizes, int n_in,
                              void* d_out, int out_size, void* d_ws, size_t ws_size,
                              hipStream_t stream) {
    const float* out_e = (const float*)d_in[0];
    const float* hidden_d = (const float*)d_in[1];
    const float* W1 = (const float*)d_in[2];
    const float* b1 = (const float*)d_in[3];
    const float* W2 = (const float*)d_in[4];
    const float* b2 = (const float*)d_in[5];
    const float* W3 = (const float*)d_in[6];

    float* out = (float*)d_out;
    float* c_out = out;                 // (1,N,H)
    float* alpha_out = out + kN * kH;   // (S,N,1)

    char* ws = (char*)d_ws;
    unsigned short* W2b = (unsigned short*)ws;                       // 2 MB
    float* h1c = (float*)(ws + (2u << 20));                          // 128 KB
    float* a_ws = (float*)(ws + (2u << 20) + (128u << 10));          // 256 KB
    float* c_part = (float*)(ws + (2u << 20) + (384u << 10));        // 2 MB
    unsigned short* Abf = (unsigned short*)(ws + (5u << 20));        // 128 MB
    const size_t needed = (5ull << 20) + (size_t)kM * kH * 2;
    const bool direct = ws_size >= needed;

    k1_h1c<<<kE, 64, 0, stream>>>(hidden_d, W1, b1, b2, h1c);
    k2_cvt<<<(kE * kH / 4) / 256, 256, 0, stream>>>(W2, W2b);
    if (direct) k0_cvtA<<<(int)((size_t)kM * kH / 4 / 256), 256, 0, stream>>>(out_e, Abf);
    (void)hipMemsetAsync(a_ws, 0, kM * sizeof(float), stream);
    if (direct)
        k3_gemm<true><<<(kM / BM) * (kE / BE), 256, 0, stream>>>(out_e, Abf, W2b, h1c, W3, a_ws);
    else
        k3_gemm<false><<<(kM / BM) * (kE / BE), 256, 0, stream>>>(out_e, Abf, W2b, h1c, W3, a_ws);
    k4_softmax<<<kN, 256, 0, stream>>>(a_ws, alpha_out);
    k5_part<<<16 * kN, 256, 0, stream>>>(out_e, alpha_out, c_part);
    k6_reduce<<<32, 256, 0, stream>>>(c_part, c_out);
}

// Round 5
// 605.073 us; speedup vs baseline: 1.1636x; 1.1294x over previous
//
#include <hip/hip_runtime.h>
#include <hip/hip_bf16.h>
#include <stdint.h>

// Problem constants
constexpr int kS = 2048;   // source length
constexpr int kN = 32;     // batch
constexpr int kH = 1024;   // hidden
constexpr int kE = 1024;   // mlp width
constexpr int kM = kS * kN;  // 65536 GEMM rows

// GEMM tiling
constexpr int BM = 128;
constexpr int BE = 128;
constexpr int BK = 64;
constexpr int KSTEPS = kH / BK;    // 16
constexpr int NTILES = (kM / BM) * (kE / BE);  // 4096
constexpr int TPX = NTILES / 8;    // tiles per XCD chunk (512)

typedef __bf16 bf16x8 __attribute__((ext_vector_type(8)));
typedef float f32x4 __attribute__((ext_vector_type(4)));

__device__ __forceinline__ float tanh_fast(float x) {
    float e = __expf(2.0f * x);
    return 1.0f - 2.0f / (e + 1.0f);
}

__device__ __forceinline__ uint32_t f2bf_rne(float f) {
    uint32_t u = __builtin_bit_cast(uint32_t, f);
    u += 0x7FFFu + ((u >> 16) & 1u);
    return u >> 16;
}

__device__ __forceinline__ uint32_t pack2bf(float lo, float hi) {
    return f2bf_rne(lo) | (f2bf_rne(hi) << 16);
}

// async global->LDS, 16B per lane, wave-uniform LDS base (HW adds lane*16)
__device__ __forceinline__ void gl_lds16(const void* g, void* l) {
    __builtin_amdgcn_global_load_lds(
        (const __attribute__((address_space(1))) uint32_t*)g,
        (__attribute__((address_space(3))) uint32_t*)l, 16, 0, 0);
}

// ---------------- K0: out_e fp32 -> bf16 copy (A operand for the GEMM)
__global__ __launch_bounds__(256) void k0_cvtA(const float* __restrict__ in,
                                               unsigned short* __restrict__ out) {
    size_t i = (size_t)blockIdx.x * 256 + threadIdx.x;  // float4 index
    float4 v = ((const float4*)in)[i];
    uint2 o;
    o.x = pack2bf(v.x, v.y);
    o.y = pack2bf(v.z, v.w);
    ((uint2*)out)[i] = o;
}

// ---------------- K1: h1c[n][e] = b1[e]+b2[e] + sum_h hidden_d[n][h]*W1[e][h]
__global__ __launch_bounds__(64) void k1_h1c(const float* __restrict__ hd,
                                             const float* __restrict__ W1,
                                             const float* __restrict__ b1,
                                             const float* __restrict__ b2,
                                             float* __restrict__ h1c) {
    int e = blockIdx.x;
    int lane = threadIdx.x;
    const float4* wrow = (const float4*)(W1 + (size_t)e * kH);
    float4 w[4];
#pragma unroll
    for (int q = 0; q < 4; ++q) w[q] = wrow[lane + q * 64];
    float bb = b1[e] + b2[e];
    for (int n = 0; n < kN; ++n) {
        const float4* hrow = (const float4*)(hd + (size_t)n * kH);
        float p = 0.f;
#pragma unroll
        for (int q = 0; q < 4; ++q) {
            float4 h4 = hrow[lane + q * 64];
            p += w[q].x * h4.x + w[q].y * h4.y + w[q].z * h4.z + w[q].w * h4.w;
        }
#pragma unroll
        for (int o = 32; o; o >>= 1) p += __shfl_xor(p, o);
        if (lane == 0) h1c[n * kE + e] = p + bb;
    }
}

// ---------------- K2: W2 fp32 -> bf16 (same [e][h] layout)
__global__ __launch_bounds__(256) void k2_cvt(const float* __restrict__ W2,
                                              unsigned short* __restrict__ W2b) {
    int i = blockIdx.x * 256 + threadIdx.x;
    float4 v = ((const float4*)W2)[i];
    uint2 o;
    o.x = pack2bf(v.x, v.y);
    o.y = pack2bf(v.z, v.w);
    ((uint2*)W2b)[i] = o;
}

// ---------------- K3: fused  a[r] = sum_e W3[e]*tanh(h1c[r&31][e] + out_e[r]@W2[e])
// 128x128 tile, BK=64, 4 waves (2x2), 16x16x32 bf16 MFMA.
// SINGLE-buffered LDS (32 KB -> 4 blocks/CU; m97 2-barrier structure, m132 lesson)
// + XCD-aware bijective tile swizzle for A-panel L2 reuse.
// DIRECT: global_load_lds staging, XOR swizzle via pre-swizzled global source chunk.
template <bool DIRECT>
__global__ __launch_bounds__(256, 4) void k3_gemm(const float* __restrict__ out_e,
                                                  const unsigned short* __restrict__ Abf,
                                                  const unsigned short* __restrict__ W2b,
                                                  const float* __restrict__ h1c,
                                                  const float* __restrict__ W3,
                                                  float* __restrict__ a_ws) {
    __shared__ __align__(16) unsigned short Abuf[BM * BK];
    __shared__ __align__(16) unsigned short Bbuf[BE * BK];

    const int tid = threadIdx.x;
    const int lane = tid & 63;
    const int w = tid >> 6;
    const int wr = w >> 1, wc = w & 1;
    const int l15 = lane & 15, lhi = lane >> 4;
    // XCD swizzle: blocks with bid%8==x land on XCD x; give each XCD a
    // contiguous run of tiles so consecutive tiles share A-panels in its L2.
    const int bid = blockIdx.x;
    const int tile = (bid & 7) * TPX + (bid >> 3);
    const int rowBase = (tile >> 3) * BM;
    const int colBase = (tile & 7) * BE;

    // accumulator init = h1c broadcast term (z = x@W2^T + h1c, applied pre-tanh)
    f32x4 acc[4][4];
#pragma unroll
    for (int m = 0; m < 4; ++m)
#pragma unroll
        for (int n = 0; n < 4; ++n)
#pragma unroll
            for (int j = 0; j < 4; ++j) {
                int rl = wr * 64 + m * 16 + lhi * 4 + j;
                int e = colBase + wc * 64 + n * 16 + l15;
                acc[m][n][j] = h1c[((rowBase + rl) & (kN - 1)) * kE + e];
            }

    // DIRECT staging: LDS linear offset L = w*4096 + i*1024 + lane*16
    //  -> row = L>>7, chunk c = (L>>4)&7. Source chunk = c ^ (row&7), row&7 = lane>>3.
    const int r8 = lane >> 3;
    const int schunk = (lane & 7) ^ r8;
    auto stage_dma = [&](const unsigned short* src, int gRowBase, int ks,
                         unsigned short* lds) {
#pragma unroll
        for (int i = 0; i < 4; ++i) {
            int row = w * 32 + i * 8 + r8;
            const void* g = src + (size_t)(gRowBase + row) * kH + ks * BK + schunk * 8;
            void* l = (char*)lds + w * 4096 + i * 1024;
            gl_lds16(g, l);
        }
    };

    // fallback reg staging (fp32 A path)
    auto stageA_load = [&](int ks, float4* regs) {
#pragma unroll
        for (int t = 0; t < 8; ++t) {
            int li = t * 256 + tid;
            int arow = li >> 4, akf = (li & 15) * 4;
            regs[t] = *(const float4*)(out_e + (size_t)(rowBase + arow) * kH + ks * BK + akf);
        }
    };
    auto stageB_load = [&](int ks, uint4* regs) {
#pragma unroll
        for (int t = 0; t < 4; ++t) {
            int li = t * 256 + tid;
            int brow = li >> 3, bk8 = (li & 7) * 8;
            regs[t] = *(const uint4*)(W2b + (size_t)(colBase + brow) * kH + ks * BK + bk8);
        }
    };
    auto stageA_write = [&](float4* regs) {
        char* base = (char*)Abuf;
#pragma unroll
        for (int t = 0; t < 8; ++t) {
            int li = t * 256 + tid;
            int arow = li >> 4, akf = (li & 15) * 4;
            int off = arow * 128 + ((akf * 2) ^ ((arow & 7) << 4));
            uint2 val;
            val.x = pack2bf(regs[t].x, regs[t].y);
            val.y = pack2bf(regs[t].z, regs[t].w);
            *(uint2*)(base + off) = val;
        }
    };
    auto stageB_write = [&](uint4* regs) {
        char* base = (char*)Bbuf;
#pragma unroll
        for (int t = 0; t < 4; ++t) {
            int li = t * 256 + tid;
            int brow = li >> 3, bk8 = (li & 7) * 8;
            int off = brow * 128 + ((bk8 * 2) ^ ((brow & 7) << 4));
            *(uint4*)(base + off) = regs[t];
        }
    };

    auto compute = [&]() {
        const char* Ab = (const char*)Abuf;
        const char* Bb = (const char*)Bbuf;
        bf16x8 af[2][4], bfr[2][4];
#pragma unroll
        for (int kk = 0; kk < 2; ++kk) {
            int kb = (kk * 32 + lhi * 8) * 2;
#pragma unroll
            for (int m = 0; m < 4; ++m) {
                int row = wr * 64 + m * 16 + l15;
                uint4 v = *(const uint4*)(Ab + row * 128 + (kb ^ ((row & 7) << 4)));
                af[kk][m] = __builtin_bit_cast(bf16x8, v);
            }
#pragma unroll
            for (int n = 0; n < 4; ++n) {
                int row = wc * 64 + n * 16 + l15;
                uint4 v = *(const uint4*)(Bb + row * 128 + (kb ^ ((row & 7) << 4)));
                bfr[kk][n] = __builtin_bit_cast(bf16x8, v);
            }
        }
#pragma unroll
        for (int kk = 0; kk < 2; ++kk)
#pragma unroll
            for (int m = 0; m < 4; ++m)
#pragma unroll
                for (int n = 0; n < 4; ++n)
                    acc[m][n] = __builtin_amdgcn_mfma_f32_16x16x32_bf16(af[kk][m], bfr[kk][n],
                                                                        acc[m][n], 0, 0, 0);
    };

    if (DIRECT) {
        stage_dma(Abf, rowBase, 0, Abuf);
        stage_dma(W2b, colBase, 0, Bbuf);
        __syncthreads();  // vmcnt(0) drain -> tile 0 ready
        for (int ks = 0; ks < KSTEPS; ++ks) {
            compute();
            __syncthreads();  // all waves done reading LDS
            if (ks + 1 < KSTEPS) {
                stage_dma(Abf, rowBase, ks + 1, Abuf);
                stage_dma(W2b, colBase, ks + 1, Bbuf);
                __syncthreads();  // DMA drained -> next tile ready
            }
        }
    } else {
        {
            float4 ar[8]; uint4 br[4];
            stageA_load(0, ar); stageB_load(0, br);
            stageA_write(ar); stageB_write(br);
        }
        __syncthreads();
        for (int ks = 0; ks < KSTEPS; ++ks) {
            float4 ar[8]; uint4 br[4];
            if (ks + 1 < KSTEPS) { stageA_load(ks + 1, ar); stageB_load(ks + 1, br); }
            compute();
            __syncthreads();
            if (ks + 1 < KSTEPS) {
                stageA_write(ar); stageB_write(br);
                __syncthreads();
            }
        }
    }

    // epilogue: tanh + W3 dot + per-row reduce across the 16-lane col groups
    float w3v[4];
#pragma unroll
    for (int n = 0; n < 4; ++n) w3v[n] = W3[colBase + wc * 64 + n * 16 + l15];
    float rs[4][4];
#pragma unroll
    for (int m = 0; m < 4; ++m)
#pragma unroll
        for (int j = 0; j < 4; ++j) {
            float v = 0.f;
#pragma unroll
            for (int n = 0; n < 4; ++n) v += w3v[n] * tanh_fast(acc[m][n][j]);
#pragma unroll
            for (int o = 1; o < 16; o <<= 1) v += __shfl_xor(v, o);
            rs[m][j] = v;
        }
    if (l15 == 0) {
#pragma unroll
        for (int m = 0; m < 4; ++m)
#pragma unroll
            for (int j = 0; j < 4; ++j)
                atomicAdd(&a_ws[rowBase + wr * 64 + m * 16 + lhi * 4 + j], rs[m][j]);
    }
}

// ---------------- K4: alpha[s][n] = softmax over s of a[s][n]
__global__ __launch_bounds__(256) void k4_softmax(const float* __restrict__ a_ws,
                                                  float* __restrict__ alpha) {
    int n = blockIdx.x;
    int tid = threadIdx.x;
    __shared__ float red[4];
    float v[8];
    float mx = -1e30f;
#pragma unroll
    for (int i = 0; i < 8; ++i) {
        v[i] = a_ws[(i * 256 + tid) * kN + n];
        mx = fmaxf(mx, v[i]);
    }
#pragma unroll
    for (int o = 32; o; o >>= 1) mx = fmaxf(mx, __shfl_xor(mx, o));
    if ((tid & 63) == 0) red[tid >> 6] = mx;
    __syncthreads();
    mx = fmaxf(fmaxf(red[0], red[1]), fmaxf(red[2], red[3]));
    float sum = 0.f;
#pragma unroll
    for (int i = 0; i < 8; ++i) { v[i] = __expf(v[i] - mx); sum += v[i]; }
#pragma unroll
    for (int o = 32; o; o >>= 1) sum += __shfl_xor(sum, o);
    __syncthreads();
    if ((tid & 63) == 0) red[tid >> 6] = sum;
    __syncthreads();
    sum = red[0] + red[1] + red[2] + red[3];
    float inv = 1.0f / sum;
#pragma unroll
    for (int i = 0; i < 8; ++i) alpha[(i * 256 + tid) * kN + n] = v[i] * inv;
}

// ---------------- K5: partial c over s-chunks of 64 (BF=true reads bf16 Abf)
template <bool BF>
__global__ __launch_bounds__(256) void k5_part(const float* __restrict__ out_e,
                                               const unsigned short* __restrict__ Abf,
                                               const float* __restrict__ alpha,
                                               float* __restrict__ c_part) {
    int n = blockIdx.x & 31;
    int sc = blockIdx.x >> 5;  // 0..31
    int tid = threadIdx.x;
    float4 acc = make_float4(0.f, 0.f, 0.f, 0.f);
    for (int s = sc * 64; s < sc * 64 + 64; ++s) {
        float al = alpha[s * kN + n];
        if (BF) {
            uint2 v = *(const uint2*)(Abf + ((size_t)s * kN + n) * kH + tid * 4);
            acc.x += al * __builtin_bit_cast(float, v.x << 16);
            acc.y += al * __builtin_bit_cast(float, v.x & 0xFFFF0000u);
            acc.z += al * __builtin_bit_cast(float, v.y << 16);
            acc.w += al * __builtin_bit_cast(float, v.y & 0xFFFF0000u);
        } else {
            float4 x = *(const float4*)(out_e + ((size_t)s * kN + n) * kH + tid * 4);
            acc.x += al * x.x; acc.y += al * x.y; acc.z += al * x.z; acc.w += al * x.w;
        }
    }
    *(float4*)(c_part + ((size_t)sc * kN + n) * kH + tid * 4) = acc;
}

// ---------------- K6: reduce 32 partials -> c[n][h]
__global__ __launch_bounds__(256) void k6_reduce(const float* __restrict__ c_part,
                                                 float* __restrict__ c) {
    int idx = blockIdx.x * 256 + threadIdx.x;  // float4 index over 8192
    float4 acc = make_float4(0.f, 0.f, 0.f, 0.f);
#pragma unroll
    for (int scn = 0; scn < 32; ++scn) {
        float4 x = ((const float4*)c_part)[scn * 8192 + idx];
        acc.x += x.x; acc.y += x.y; acc.z += x.z; acc.w += x.w;
    }
    ((float4*)c)[idx] = acc;
}

extern "C" void kernel_launch(void* const* d_in, const int* in_sizes, int n_in,
                              void* d_out, int out_size, void* d_ws, size_t ws_size,
                              hipStream_t stream) {
    const float* out_e = (const float*)d_in[0];
    const float* hidden_d = (const float*)d_in[1];
    const float* W1 = (const float*)d_in[2];
    const float* b1 = (const float*)d_in[3];
    const float* W2 = (const float*)d_in[4];
    const float* b2 = (const float*)d_in[5];
    const float* W3 = (const float*)d_in[6];

    float* out = (float*)d_out;
    float* c_out = out;                 // (1,N,H)
    float* alpha_out = out + kN * kH;   // (S,N,1)

    char* ws = (char*)d_ws;
    const size_t oW2b = 0;
    const size_t oH1c = 2ull << 20;                     // 2 MB
    const size_t oAws = oH1c + (128ull << 10);          // +128 KB
    const size_t oCpt = oAws + (256ull << 10);          // +256 KB
    const size_t oAbf = oCpt + (4ull << 20);            // +4 MB (32 chunks)
    unsigned short* W2b = (unsigned short*)(ws + oW2b);
    float* h1c = (float*)(ws + oH1c);
    float* a_ws = (float*)(ws + oAws);
    float* c_part = (float*)(ws + oCpt);
    unsigned short* Abf = (unsigned short*)(ws + oAbf);
    const size_t needed = oAbf + (size_t)kM * kH * 2;
    const bool direct = ws_size >= needed;

    k1_h1c<<<kE, 64, 0, stream>>>(hidden_d, W1, b1, b2, h1c);
    k2_cvt<<<(kE * kH / 4) / 256, 256, 0, stream>>>(W2, W2b);
    if (direct) k0_cvtA<<<(int)((size_t)kM * kH / 4 / 256), 256, 0, stream>>>(out_e, Abf);
    (void)hipMemsetAsync(a_ws, 0, kM * sizeof(float), stream);
    if (direct)
        k3_gemm<true><<<NTILES, 256, 0, stream>>>(out_e, Abf, W2b, h1c, W3, a_ws);
    else
        k3_gemm<false><<<NTILES, 256, 0, stream>>>(out_e, Abf, W2b, h1c, W3, a_ws);
    k4_softmax<<<kN, 256, 0, stream>>>(a_ws, alpha_out);
    if (direct)
        k5_part<true><<<32 * kN, 256, 0, stream>>>(out_e, Abf, alpha_out, c_part);
    else
        k5_part<false><<<32 * kN, 256, 0, stream>>>(out_e, Abf, alpha_out, c_part);
    k6_reduce<<<32, 256, 0, stream>>>(c_part, c_out);
}